// Round 3
// baseline (400.186 us; speedup 1.0000x reference)
//
#include <hip/hip_runtime.h>
#include <math.h>

#define DIM 768
#define HEADS 4
#define HDIM 3072   // HEADS*DIM
#define BATCH 128

// ---------------------------------------------------------------------------
// Batched GEMM v2: C = A @ B^T (+bias), descriptor-batched (R1), now with
// register-prefetch software pipeline (R2: round-2 profile showed the worst
// stage at 93us / VALU 36% / HBM 6% -- per-K-tile global latency was fully
// exposed at 3.5 waves/SIMD). Tile BM=32 x BN=64 x BK=32, 128 threads,
// 4x4 outputs/thread (16 FMA per 8 LDS floats).
// ---------------------------------------------------------------------------
struct GemmDesc {
    const float* A;   // M x K, row stride lda
    const float* B;   // N x K, row stride ldb
    const float* bias;
    float* C;         // M x N, row stride ldc
    int lda, ldb, ldc;
    int M, N, K;
    int blockBase;    // first 1-D block id of this sub-problem
    int nTiles;       // N/64
    int pad;
};
#define MAXD 12
struct GemmBatch { GemmDesc d[MAXD]; int nDesc; };

__global__ __launch_bounds__(128) void gemm_batch(GemmBatch batch)
{
    __shared__ float As[32][33];   // [k][m], +1 pad: compute reads cover 32 banks
    __shared__ float Bs[32][65];   // [k][n]

    int bid = blockIdx.x;
    int i = 0;
    while (i + 1 < batch.nDesc && bid >= batch.d[i + 1].blockBase) ++i;
    const GemmDesc g = batch.d[i];
    int lb = bid - g.blockBase;
    int mt = lb / g.nTiles;
    int nt = lb - mt * g.nTiles;

    const float* __restrict__ A = g.A;
    const float* __restrict__ B = g.B;
    const int lda = g.lda, ldb = g.ldb;
    const int M = g.M, K = g.K;
    const int m0 = mt * 32;
    const int n0 = nt * 64;

    const int tid = threadIdx.x;
    // staging thread mapping
    const int lk4 = (tid & 7) * 4;   // k offset 0,4,...,28
    const int lr  = tid >> 3;        // 0..15
    // compute thread mapping (4m x 4n per thread)
    const int tm4 = (tid & 7) * 4;   // m 0..31
    const int tn4 = (tid >> 3) * 4;  // n 0..63

    float acc[4][4];
#pragma unroll
    for (int a = 0; a < 4; ++a)
#pragma unroll
        for (int b = 0; b < 4; ++b) acc[a][b] = 0.f;

    float4 na0, na1, nb0, nb1, nb2, nb3;
    const float4 fz = { 0.f, 0.f, 0.f, 0.f };

    auto loadTile = [&](int k0) {
        const float* ap = A + k0 + lk4;
        int ma = m0 + lr, mb = m0 + lr + 16;
        na0 = (ma < M) ? *(const float4*)(ap + (long)ma * lda) : fz;
        na1 = (mb < M) ? *(const float4*)(ap + (long)mb * lda) : fz;
        const float* bp = B + (long)(n0 + lr) * ldb + k0 + lk4;
        nb0 = *(const float4*)(bp);
        nb1 = *(const float4*)(bp + (long)16 * ldb);
        nb2 = *(const float4*)(bp + (long)32 * ldb);
        nb3 = *(const float4*)(bp + (long)48 * ldb);
    };
    auto writeLDS = [&]() {
        const float* a0 = (const float*)&na0;
        const float* a1 = (const float*)&na1;
        const float* b0 = (const float*)&nb0;
        const float* b1 = (const float*)&nb1;
        const float* b2 = (const float*)&nb2;
        const float* b3 = (const float*)&nb3;
#pragma unroll
        for (int j = 0; j < 4; ++j) {
            As[lk4 + j][lr]      = a0[j];
            As[lk4 + j][lr + 16] = a1[j];
            Bs[lk4 + j][lr]      = b0[j];
            Bs[lk4 + j][lr + 16] = b1[j];
            Bs[lk4 + j][lr + 32] = b2[j];
            Bs[lk4 + j][lr + 48] = b3[j];
        }
    };

    const int nk = K >> 5;
    loadTile(0);
    writeLDS();
    __syncthreads();

    for (int t = 0; t < nk; ++t) {
        if (t + 1 < nk) loadTile((t + 1) * 32);   // in flight during compute
#pragma unroll
        for (int kk = 0; kk < 32; ++kk) {
            float4 av = *(const float4*)&As[kk][tm4];
            float4 bv = *(const float4*)&Bs[kk][tn4];
            const float* ap = (const float*)&av;
            const float* bp = (const float*)&bv;
#pragma unroll
            for (int a = 0; a < 4; ++a)
#pragma unroll
                for (int b = 0; b < 4; ++b)
                    acc[a][b] += ap[a] * bp[b];
        }
        __syncthreads();
        if (t + 1 < nk) { writeLDS(); __syncthreads(); }
    }

    // epilogue
    float4 bias4 = fz;
    if (g.bias) bias4 = *(const float4*)(g.bias + n0 + tn4);
    const float* bb = (const float*)&bias4;
#pragma unroll
    for (int a = 0; a < 4; ++a) {
        int m = m0 + tm4 + a;
        if (m < M) {
            float4 o;
            o.x = acc[a][0] + bb[0];
            o.y = acc[a][1] + bb[1];
            o.z = acc[a][2] + bb[2];
            o.w = acc[a][3] + bb[3];
            *(float4*)&g.C[(long)m * g.ldc + n0 + tn4] = o;
        }
    }
}

// ---------------------------------------------------------------------------
// Fused attention row-0 + FC + 2x LN + score. One 256-thr block per (b,t).
// Both levels in ONE dispatch via 2-entry descriptor table.
// ---------------------------------------------------------------------------
struct ScoreDesc {
    const float *tok_q, *tok_k, *k_task, *U_tok, *U_task, *tokens;
    const float *fcb, *lng, *lnb, *slng, *slnb, *sw, *sbias;
    int T, outOff, blockBase, pad;
};
struct ScoreBatch { ScoreDesc d[2]; };

__device__ inline void block_reduce2(float& a, float& b, float* redA, float* redB, int tid)
{
    int lane = tid & 63, wave = tid >> 6;
#pragma unroll
    for (int off = 32; off; off >>= 1) {
        a += __shfl_down(a, off);
        b += __shfl_down(b, off);
    }
    if (lane == 0) { redA[wave] = a; redB[wave] = b; }
    __syncthreads();
    a = redA[0] + redA[1] + redA[2] + redA[3];
    b = redB[0] + redB[1] + redB[2] + redB[3];
    __syncthreads();
}

__global__ __launch_bounds__(256) void score_kernel(ScoreBatch batch, float* __restrict__ out)
{
    const int si = (blockIdx.x >= batch.d[1].blockBase) ? 1 : 0;
    const ScoreDesc g = batch.d[si];
    const int bid = blockIdx.x - g.blockBase;
    const int T = g.T;
    const int b = bid / T;
    const int t = bid - b * T;
    const int tid = threadIdx.x;
    const int lane = tid & 63;
    const int wave = tid >> 6;   // == head

    __shared__ float coef[HEADS][2];
    __shared__ float redA[4], redB[4];

    // ---- per-head attention row-0 softmax weights (float4 dots) ----
    {
        const float4* q4  = (const float4*)(g.tok_q  + (long)t * HDIM + wave * DIM);
        const float4* kt4 = (const float4*)(g.tok_k  + (long)t * HDIM + wave * DIM);
        const float4* kb4 = (const float4*)(g.k_task + (long)b * HDIM + wave * DIM);
        float s00 = 0.f, s01 = 0.f;
#pragma unroll
        for (int j = 0; j < 3; ++j) {
            int idx = lane + 64 * j;          // < 192
            float4 qv = q4[idx], kt = kt4[idx], kb = kb4[idx];
            s00 += qv.x * kt.x + qv.y * kt.y + qv.z * kt.z + qv.w * kt.w;
            s01 += qv.x * kb.x + qv.y * kb.y + qv.z * kb.z + qv.w * kb.w;
        }
#pragma unroll
        for (int off = 32; off; off >>= 1) {
            s00 += __shfl_down(s00, off);
            s01 += __shfl_down(s01, off);
        }
        if (lane == 0) {
            const float scale = 0.03608439182435161f;  // 1/sqrt(768)
            float x0 = s00 * scale, x1 = s01 * scale;
            float mx = fmaxf(x0, x1);
            float e0 = expf(x0 - mx), e1 = expf(x1 - mx);
            float inv = 1.f / (e0 + e1);
            coef[wave][0] = e0 * inv;
            coef[wave][1] = e1 * inv;
        }
    }
    __syncthreads();

    const float c00 = coef[0][0], c01 = coef[0][1];
    const float c10 = coef[1][0], c11 = coef[1][1];
    const float c20 = coef[2][0], c21 = coef[2][1];
    const float c30 = coef[3][0], c31 = coef[3][1];

    // ---- r = fc(o0) + fcb + x0 ----
    float r[3];
    float sum = 0.f, sq = 0.f;
    const float* Ut = g.U_tok  + (long)t * HDIM;
    const float* Ub = g.U_task + (long)b * HDIM;
#pragma unroll
    for (int j = 0; j < 3; ++j) {
        int d = tid + j * 256;
        float v = g.fcb[d] + g.tokens[(long)t * DIM + d];
        v += c00 * Ut[d]           + c01 * Ub[d];
        v += c10 * Ut[DIM + d]     + c11 * Ub[DIM + d];
        v += c20 * Ut[2 * DIM + d] + c21 * Ub[2 * DIM + d];
        v += c30 * Ut[3 * DIM + d] + c31 * Ub[3 * DIM + d];
        r[j] = v;
        sum += v;
        sq += v * v;
    }
    block_reduce2(sum, sq, redA, redB, tid);
    float mean = sum * (1.f / DIM);
    float var = sq * (1.f / DIM) - mean * mean;
    float inv = rsqrtf(var + 1e-5f);

    float y[3];
    float sum2 = 0.f, sq2 = 0.f;
#pragma unroll
    for (int j = 0; j < 3; ++j) {
        int d = tid + j * 256;
        float v = (r[j] - mean) * inv * g.lng[d] + g.lnb[d];
        y[j] = v;
        sum2 += v;
        sq2 += v * v;
    }
    block_reduce2(sum2, sq2, redA, redB, tid);
    float mean2 = sum2 * (1.f / DIM);
    float var2 = sq2 * (1.f / DIM) - mean2 * mean2;
    float inv2 = rsqrtf(var2 + 1e-5f);

    float partial = 0.f, dummy = 0.f;
#pragma unroll
    for (int j = 0; j < 3; ++j) {
        int d = tid + j * 256;
        float c = (y[j] - mean2) * inv2 * g.slng[d] + g.slnb[d];
        partial += c * g.sw[d];
    }
    block_reduce2(partial, dummy, redA, redB, tid);
    if (tid == 0) out[(long)b * 80 + g.outOff + t] = partial + g.sbias[0];
}

// ---------------------------------------------------------------------------
extern "C" void kernel_launch(void* const* d_in, const int* in_sizes, int n_in,
                              void* d_out, int out_size, void* d_ws, size_t ws_size,
                              hipStream_t stream)
{
    const float* task_emb    = (const float*)d_in[0];
    const float* tokens_l1   = (const float*)d_in[1];
    const float* tokens_l2   = (const float*)d_in[2];
    const float* task_proj_w = (const float*)d_in[3];
    const float* task_proj_b = (const float*)d_in[4];

    const float* wq1  = (const float*)d_in[5];
    const float* wk1  = (const float*)d_in[6];
    const float* wv1  = (const float*)d_in[7];
    const float* fcw1 = (const float*)d_in[8];
    const float* fcb1 = (const float*)d_in[9];
    const float* lng1 = (const float*)d_in[10];
    const float* lnb1 = (const float*)d_in[11];
    const float* slng1= (const float*)d_in[12];
    const float* slnb1= (const float*)d_in[13];
    const float* sw1  = (const float*)d_in[14];
    const float* sb1  = (const float*)d_in[15];

    const float* wq2  = (const float*)d_in[16];
    const float* wk2  = (const float*)d_in[17];
    const float* wv2  = (const float*)d_in[18];
    const float* fcw2 = (const float*)d_in[19];
    const float* fcb2 = (const float*)d_in[20];
    const float* lng2 = (const float*)d_in[21];
    const float* lnb2 = (const float*)d_in[22];
    const float* slng2= (const float*)d_in[23];
    const float* slnb2= (const float*)d_in[24];
    const float* sw2  = (const float*)d_in[25];
    const float* sb2  = (const float*)d_in[26];

    float* out = (float*)d_out;

    float* ws = (float*)d_ws;
    float* task_p   = ws;
    float* tq1      = task_p   +  98304;
    float* tk1      = tq1      +  49152;
    float* tv1      = tk1      +  49152;
    float* ut1      = tv1      +  49152;
    float* tq2      = ut1      +  49152;
    float* tk2      = tq2      + 196608;
    float* tv2      = tk2      + 196608;
    float* ut2      = tv2      + 196608;
    float* ktask1   = ut2      + 196608;
    float* vtask1   = ktask1   + 393216;
    float* utask1   = vtask1   + 393216;
    float* ktask2   = utask1   + 393216;
    float* vtask2   = ktask2   + 393216;
    float* utask2   = vtask2   + 393216;

    auto mkDesc = [](const float* A, int lda, const float* B, int ldb,
                     const float* bias, float* C, int ldc,
                     int M, int N, int K, int base) {
        GemmDesc g;
        g.A = A; g.B = B; g.bias = bias; g.C = C;
        g.lda = lda; g.ldb = ldb; g.ldc = ldc;
        g.M = M; g.N = N; g.K = K;
        g.blockBase = base; g.nTiles = N / 64; g.pad = 0;
        return g;
    };
    auto blocksOf = [](int M, int N) { return ((M + 31) / 32) * (N / 64); };

    // ---- stage A: task_p + token q/k/v projections ----
    {
        GemmBatch ba; int base = 0, nd = 0;
        ba.d[nd++] = mkDesc(task_emb, DIM, task_proj_w, DIM, task_proj_b,
                            task_p, DIM, BATCH, DIM, DIM, base);
        base += blocksOf(BATCH, DIM);
        const float* tA[2] = { tokens_l1, tokens_l2 };
        int tT[2] = { 16, 64 };
        const float* tW[2][3] = { { wq1, wk1, wv1 }, { wq2, wk2, wv2 } };
        float* tC[2][3] = { { tq1, tk1, tv1 }, { tq2, tk2, tv2 } };
        for (int l = 0; l < 2; ++l)
            for (int w = 0; w < 3; ++w) {
                ba.d[nd++] = mkDesc(tA[l], DIM, tW[l][w], DIM, nullptr,
                                    tC[l][w], HDIM, tT[l], HDIM, DIM, base);
                base += blocksOf(tT[l], HDIM);
            }
        ba.nDesc = nd;
        gemm_batch<<<dim3(base), dim3(128), 0, stream>>>(ba);
    }

    // ---- stage B: k_task/v_task + U_tok per head ----
    {
        GemmBatch bb; int base = 0, nd = 0;
        const float* kw[2] = { wk1, wk2 };
        const float* vw[2] = { wv1, wv2 };
        float* kc[2] = { ktask1, ktask2 };
        float* vc[2] = { vtask1, vtask2 };
        for (int l = 0; l < 2; ++l) {
            bb.d[nd++] = mkDesc(task_p, DIM, kw[l], DIM, nullptr,
                                kc[l], HDIM, BATCH, HDIM, DIM, base);
            base += blocksOf(BATCH, HDIM);
            bb.d[nd++] = mkDesc(task_p, DIM, vw[l], DIM, nullptr,
                                vc[l], HDIM, BATCH, HDIM, DIM, base);
            base += blocksOf(BATCH, HDIM);
        }
        const float* fw[2] = { fcw1, fcw2 };
        float* tv[2] = { tv1, tv2 };
        float* ut[2] = { ut1, ut2 };
        int tT[2] = { 16, 64 };
        for (int l = 0; l < 2; ++l)
            for (int h = 0; h < HEADS; ++h) {
                bb.d[nd++] = mkDesc(tv[l] + h * DIM, HDIM, fw[l] + h * DIM, HDIM,
                                    nullptr, ut[l] + h * DIM, HDIM,
                                    tT[l], DIM, DIM, base);
                base += blocksOf(tT[l], DIM);
            }
        bb.nDesc = nd;
        gemm_batch<<<dim3(base), dim3(128), 0, stream>>>(bb);
    }

    // ---- stage C: U_task per head per level ----
    {
        GemmBatch bc; int base = 0, nd = 0;
        const float* fw[2] = { fcw1, fcw2 };
        float* vt[2] = { vtask1, vtask2 };
        float* utk[2] = { utask1, utask2 };
        for (int l = 0; l < 2; ++l)
            for (int h = 0; h < HEADS; ++h) {
                bc.d[nd++] = mkDesc(vt[l] + h * DIM, HDIM, fw[l] + h * DIM, HDIM,
                                    nullptr, utk[l] + h * DIM, HDIM,
                                    BATCH, DIM, DIM, base);
                base += blocksOf(BATCH, DIM);
            }
        bc.nDesc = nd;
        gemm_batch<<<dim3(base), dim3(128), 0, stream>>>(bc);
    }

    // ---- stage D: both score levels, one dispatch ----
    {
        ScoreBatch sb;
        sb.d[0].tok_q = tq1; sb.d[0].tok_k = tk1; sb.d[0].k_task = ktask1;
        sb.d[0].U_tok = ut1; sb.d[0].U_task = utask1; sb.d[0].tokens = tokens_l1;
        sb.d[0].fcb = fcb1; sb.d[0].lng = lng1; sb.d[0].lnb = lnb1;
        sb.d[0].slng = slng1; sb.d[0].slnb = slnb1; sb.d[0].sw = sw1; sb.d[0].sbias = sb1;
        sb.d[0].T = 16; sb.d[0].outOff = 0; sb.d[0].blockBase = 0; sb.d[0].pad = 0;
        sb.d[1].tok_q = tq2; sb.d[1].tok_k = tk2; sb.d[1].k_task = ktask2;
        sb.d[1].U_tok = ut2; sb.d[1].U_task = utask2; sb.d[1].tokens = tokens_l2;
        sb.d[1].fcb = fcb2; sb.d[1].lng = lng2; sb.d[1].lnb = lnb2;
        sb.d[1].slng = slng2; sb.d[1].slnb = slnb2; sb.d[1].sw = sw2; sb.d[1].sbias = sb2;
        sb.d[1].T = 64; sb.d[1].outOff = 16; sb.d[1].blockBase = BATCH * 16; sb.d[1].pad = 0;
        score_kernel<<<dim3(BATCH * 16 + BATCH * 64), dim3(256), 0, stream>>>(sb, out);
    }
}

// Round 4
// 276.665 us; speedup vs baseline: 1.4465x; 1.4465x over previous
//
#include <hip/hip_runtime.h>
#include <math.h>

#define DIM 768
#define HEADS 4
#define HDIM 3072   // HEADS*DIM
#define BATCH 128

// ---------------------------------------------------------------------------
// R3 history: fp32 VALU GEMM peaked at 28% VALUBusy / 9% occupancy (VGPR 172
// cliff). fp32 floor is 34us at 100% issue -- wrong regime. This round: bf16
// MFMA (16x16x32), fragment-ordered LDS (any consistent (g,j)->k bijection is
// mathematically exact for A&B pairs), fp32 accumulate, double-buffered,
// 1 barrier/K-step. Tile BM=32 x BN=128 x BK=64, 256 thr (4 waves, 1m x 4n).
// ---------------------------------------------------------------------------
typedef __attribute__((ext_vector_type(8))) short bfrag;   // 8 bf16 = 4 VGPR
typedef __attribute__((ext_vector_type(4))) float f32x4;

struct GemmDesc {
    const float* A;   // M x K, row stride lda
    const float* B;   // N x K, row stride ldb
    const float* bias;
    float* C;         // M x N, row stride ldc
    int lda, ldb, ldc;
    int M, N, K;
    int blockBase;    // first 1-D block id of this sub-problem
    int nTiles;       // N/128
};
#define MAXD 12
struct GemmBatch { GemmDesc d[MAXD]; int nDesc; };

__device__ inline short f2bf(float f) {   // RTNE fp32 -> bf16
    unsigned u = __float_as_uint(f);
    u += 0x7FFF + ((u >> 16) & 1);
    return (short)(u >> 16);
}

__global__ __launch_bounds__(256) void gemm_bf16(GemmBatch batch)
{
    // fragment-ordered bf16 tiles: 1KB region per (16-row-group x 32-k-block);
    // slot S (8B) decomposes as region=S>>7, lane=(S&127)>>1, j2=S&1.
    __shared__ __attribute__((aligned(16))) short Asl[2][2048];  // 32x64
    __shared__ __attribute__((aligned(16))) short Bsl[2][8192];  // 128x64

    int bid = blockIdx.x;
    int di = 0;
    while (di + 1 < batch.nDesc && bid >= batch.d[di + 1].blockBase) ++di;
    const GemmDesc g = batch.d[di];
    int lb = bid - g.blockBase;
    int mt = lb / g.nTiles;
    int nt = lb - mt * g.nTiles;
    const int m0 = mt * 32, n0 = nt * 128;
    const int M = g.M, lda = g.lda, ldb = g.ldb;
    const float* __restrict__ A = g.A;
    const float* __restrict__ B = g.B;

    const int tid = threadIdx.x;
    const int lane = tid & 63;
    const int w = tid >> 6;          // wave id = n-strip (32 cols each)

    // ---- precompute staging offsets (slot -> global (row,k)) ----
    int aoff[2]; bool aok[2];
#pragma unroll
    for (int ia = 0; ia < 2; ++ia) {
        int S = tid + 256 * ia;
        int reg = S >> 7, h = S & 127, l = h >> 1, j2 = h & 1;
        int mg = reg >> 1, kb = reg & 1;
        int m = mg * 16 + (l & 15);
        int k = kb * 32 + (l >> 4) * 8 + j2 * 4;
        aok[ia] = (m0 + m) < M;
        aoff[ia] = (m0 + m) * lda + k;
    }
    int boff[8];
#pragma unroll
    for (int ib = 0; ib < 8; ++ib) {
        int S = tid + 256 * ib;
        int reg = S >> 7, h = S & 127, l = h >> 1, j2 = h & 1;
        int ng = reg >> 1, kb = reg & 1;
        int n = ng * 16 + (l & 15);
        int k = kb * 32 + (l >> 4) * 8 + j2 * 4;
        boff[ib] = (n0 + n) * ldb + k;
    }

    float4 pa[2], pb[8];
    const float4 fz = { 0.f, 0.f, 0.f, 0.f };

    auto LOADT = [&](int k0) {
#pragma unroll
        for (int ia = 0; ia < 2; ++ia)
            pa[ia] = aok[ia] ? *(const float4*)(A + aoff[ia] + k0) : fz;
#pragma unroll
        for (int ib = 0; ib < 8; ++ib)
            pb[ib] = *(const float4*)(B + boff[ib] + k0);
    };
    auto WRITET = [&](int bf) {
#pragma unroll
        for (int ia = 0; ia < 2; ++ia) {
            short4 s;
            s.x = f2bf(pa[ia].x); s.y = f2bf(pa[ia].y);
            s.z = f2bf(pa[ia].z); s.w = f2bf(pa[ia].w);
            *(short4*)&Asl[bf][(tid + 256 * ia) * 4] = s;
        }
#pragma unroll
        for (int ib = 0; ib < 8; ++ib) {
            short4 s;
            s.x = f2bf(pb[ib].x); s.y = f2bf(pb[ib].y);
            s.z = f2bf(pb[ib].z); s.w = f2bf(pb[ib].w);
            *(short4*)&Bsl[bf][(tid + 256 * ib) * 4] = s;
        }
    };

    f32x4 acc[2][2];
#pragma unroll
    for (int a = 0; a < 2; ++a)
#pragma unroll
        for (int b = 0; b < 2; ++b) acc[a][b] = (f32x4){0.f, 0.f, 0.f, 0.f};

    const int nk = g.K >> 6;   // K-steps of 64
    LOADT(0);
    WRITET(0);
    __syncthreads();

    int buf = 0;
    for (int t = 0; t < nk; ++t) {
        bool more = (t + 1 < nk);
        if (more) LOADT((t + 1) << 6);     // HBM latency hides under MFMA
#pragma unroll
        for (int kb = 0; kb < 2; ++kb) {
            bfrag a0 = *(const bfrag*)&Asl[buf][(0 * 2 + kb) * 512 + lane * 8];
            bfrag a1 = *(const bfrag*)&Asl[buf][(1 * 2 + kb) * 512 + lane * 8];
            bfrag b0 = *(const bfrag*)&Bsl[buf][((w * 2 + 0) * 2 + kb) * 512 + lane * 8];
            bfrag b1 = *(const bfrag*)&Bsl[buf][((w * 2 + 1) * 2 + kb) * 512 + lane * 8];
            acc[0][0] = __builtin_amdgcn_mfma_f32_16x16x32_bf16(a0, b0, acc[0][0], 0, 0, 0);
            acc[0][1] = __builtin_amdgcn_mfma_f32_16x16x32_bf16(a0, b1, acc[0][1], 0, 0, 0);
            acc[1][0] = __builtin_amdgcn_mfma_f32_16x16x32_bf16(a1, b0, acc[1][0], 0, 0, 0);
            acc[1][1] = __builtin_amdgcn_mfma_f32_16x16x32_bf16(a1, b1, acc[1][1], 0, 0, 0);
        }
        if (more) WRITET(buf ^ 1);   // other buffer: no intra-iter hazard
        __syncthreads();             // single barrier per K-step
        buf ^= 1;
    }

    // ---- epilogue: D layout col=lane&15, row=(lane>>4)*4+r (m89-verified) ----
    const int gq = lane >> 4;
    const int cn = lane & 15;
#pragma unroll
    for (int fn = 0; fn < 2; ++fn) {
        int n = n0 + w * 32 + fn * 16 + cn;
        float bv = g.bias ? g.bias[n] : 0.f;
#pragma unroll
        for (int fm = 0; fm < 2; ++fm) {
#pragma unroll
            for (int r = 0; r < 4; ++r) {
                int m = m0 + fm * 16 + gq * 4 + r;
                if (m < M) g.C[(long)m * g.ldc + n] = acc[fm][fn][r] + bv;
            }
        }
    }
}

// ---------------------------------------------------------------------------
// Fused attention row-0 + FC + 2x LN + score (unchanged from R3 -- correct,
// not yet the bottleneck). One 256-thr block per (b,t); both levels batched.
// ---------------------------------------------------------------------------
struct ScoreDesc {
    const float *tok_q, *tok_k, *k_task, *U_tok, *U_task, *tokens;
    const float *fcb, *lng, *lnb, *slng, *slnb, *sw, *sbias;
    int T, outOff, blockBase, pad;
};
struct ScoreBatch { ScoreDesc d[2]; };

__device__ inline void block_reduce2(float& a, float& b, float* redA, float* redB, int tid)
{
    int lane = tid & 63, wave = tid >> 6;
#pragma unroll
    for (int off = 32; off; off >>= 1) {
        a += __shfl_down(a, off);
        b += __shfl_down(b, off);
    }
    if (lane == 0) { redA[wave] = a; redB[wave] = b; }
    __syncthreads();
    a = redA[0] + redA[1] + redA[2] + redA[3];
    b = redB[0] + redB[1] + redB[2] + redB[3];
    __syncthreads();
}

__global__ __launch_bounds__(256) void score_kernel(ScoreBatch batch, float* __restrict__ out)
{
    const int si = (blockIdx.x >= batch.d[1].blockBase) ? 1 : 0;
    const ScoreDesc g = batch.d[si];
    const int bid = blockIdx.x - g.blockBase;
    const int T = g.T;
    const int b = bid / T;
    const int t = bid - b * T;
    const int tid = threadIdx.x;
    const int lane = tid & 63;
    const int wave = tid >> 6;   // == head

    __shared__ float coef[HEADS][2];
    __shared__ float redA[4], redB[4];

    {
        const float4* q4  = (const float4*)(g.tok_q  + (long)t * HDIM + wave * DIM);
        const float4* kt4 = (const float4*)(g.tok_k  + (long)t * HDIM + wave * DIM);
        const float4* kb4 = (const float4*)(g.k_task + (long)b * HDIM + wave * DIM);
        float s00 = 0.f, s01 = 0.f;
#pragma unroll
        for (int j = 0; j < 3; ++j) {
            int idx = lane + 64 * j;
            float4 qv = q4[idx], kt = kt4[idx], kb = kb4[idx];
            s00 += qv.x * kt.x + qv.y * kt.y + qv.z * kt.z + qv.w * kt.w;
            s01 += qv.x * kb.x + qv.y * kb.y + qv.z * kb.z + qv.w * kb.w;
        }
#pragma unroll
        for (int off = 32; off; off >>= 1) {
            s00 += __shfl_down(s00, off);
            s01 += __shfl_down(s01, off);
        }
        if (lane == 0) {
            const float scale = 0.03608439182435161f;  // 1/sqrt(768)
            float x0 = s00 * scale, x1 = s01 * scale;
            float mx = fmaxf(x0, x1);
            float e0 = expf(x0 - mx), e1 = expf(x1 - mx);
            float inv = 1.f / (e0 + e1);
            coef[wave][0] = e0 * inv;
            coef[wave][1] = e1 * inv;
        }
    }
    __syncthreads();

    const float c00 = coef[0][0], c01 = coef[0][1];
    const float c10 = coef[1][0], c11 = coef[1][1];
    const float c20 = coef[2][0], c21 = coef[2][1];
    const float c30 = coef[3][0], c31 = coef[3][1];

    float r[3];
    float sum = 0.f, sq = 0.f;
    const float* Ut = g.U_tok  + (long)t * HDIM;
    const float* Ub = g.U_task + (long)b * HDIM;
#pragma unroll
    for (int j = 0; j < 3; ++j) {
        int d = tid + j * 256;
        float v = g.fcb[d] + g.tokens[(long)t * DIM + d];
        v += c00 * Ut[d]           + c01 * Ub[d];
        v += c10 * Ut[DIM + d]     + c11 * Ub[DIM + d];
        v += c20 * Ut[2 * DIM + d] + c21 * Ub[2 * DIM + d];
        v += c30 * Ut[3 * DIM + d] + c31 * Ub[3 * DIM + d];
        r[j] = v;
        sum += v;
        sq += v * v;
    }
    block_reduce2(sum, sq, redA, redB, tid);
    float mean = sum * (1.f / DIM);
    float var = sq * (1.f / DIM) - mean * mean;
    float inv = rsqrtf(var + 1e-5f);

    float y[3];
    float sum2 = 0.f, sq2 = 0.f;
#pragma unroll
    for (int j = 0; j < 3; ++j) {
        int d = tid + j * 256;
        float v = (r[j] - mean) * inv * g.lng[d] + g.lnb[d];
        y[j] = v;
        sum2 += v;
        sq2 += v * v;
    }
    block_reduce2(sum2, sq2, redA, redB, tid);
    float mean2 = sum2 * (1.f / DIM);
    float var2 = sq2 * (1.f / DIM) - mean2 * mean2;
    float inv2 = rsqrtf(var2 + 1e-5f);

    float partial = 0.f, dummy = 0.f;
#pragma unroll
    for (int j = 0; j < 3; ++j) {
        int d = tid + j * 256;
        float c = (y[j] - mean2) * inv2 * g.slng[d] + g.slnb[d];
        partial += c * g.sw[d];
    }
    block_reduce2(partial, dummy, redA, redB, tid);
    if (tid == 0) out[(long)b * 80 + g.outOff + t] = partial + g.sbias[0];
}

// ---------------------------------------------------------------------------
extern "C" void kernel_launch(void* const* d_in, const int* in_sizes, int n_in,
                              void* d_out, int out_size, void* d_ws, size_t ws_size,
                              hipStream_t stream)
{
    const float* task_emb    = (const float*)d_in[0];
    const float* tokens_l1   = (const float*)d_in[1];
    const float* tokens_l2   = (const float*)d_in[2];
    const float* task_proj_w = (const float*)d_in[3];
    const float* task_proj_b = (const float*)d_in[4];

    const float* wq1  = (const float*)d_in[5];
    const float* wk1  = (const float*)d_in[6];
    const float* wv1  = (const float*)d_in[7];
    const float* fcw1 = (const float*)d_in[8];
    const float* fcb1 = (const float*)d_in[9];
    const float* lng1 = (const float*)d_in[10];
    const float* lnb1 = (const float*)d_in[11];
    const float* slng1= (const float*)d_in[12];
    const float* slnb1= (const float*)d_in[13];
    const float* sw1  = (const float*)d_in[14];
    const float* sb1  = (const float*)d_in[15];

    const float* wq2  = (const float*)d_in[16];
    const float* wk2  = (const float*)d_in[17];
    const float* wv2  = (const float*)d_in[18];
    const float* fcw2 = (const float*)d_in[19];
    const float* fcb2 = (const float*)d_in[20];
    const float* lng2 = (const float*)d_in[21];
    const float* lnb2 = (const float*)d_in[22];
    const float* slng2= (const float*)d_in[23];
    const float* slnb2= (const float*)d_in[24];
    const float* sw2  = (const float*)d_in[25];
    const float* sb2  = (const float*)d_in[26];

    float* out = (float*)d_out;

    float* ws = (float*)d_ws;
    float* task_p   = ws;
    float* tq1      = task_p   +  98304;
    float* tk1      = tq1      +  49152;
    float* tv1      = tk1      +  49152;
    float* ut1      = tv1      +  49152;
    float* tq2      = ut1      +  49152;
    float* tk2      = tq2      + 196608;
    float* tv2      = tk2      + 196608;
    float* ut2      = tv2      + 196608;
    float* ktask1   = ut2      + 196608;
    float* vtask1   = ktask1   + 393216;
    float* utask1   = vtask1   + 393216;
    float* ktask2   = utask1   + 393216;
    float* vtask2   = ktask2   + 393216;
    float* utask2   = vtask2   + 393216;

    auto mkDesc = [](const float* A, int lda, const float* B, int ldb,
                     const float* bias, float* C, int ldc,
                     int M, int N, int K, int base) {
        GemmDesc g;
        g.A = A; g.B = B; g.bias = bias; g.C = C;
        g.lda = lda; g.ldb = ldb; g.ldc = ldc;
        g.M = M; g.N = N; g.K = K;
        g.blockBase = base; g.nTiles = N / 128;
        return g;
    };
    auto blocksOf = [](int M, int N) { return ((M + 31) / 32) * (N / 128); };

    // ---- stage A: task_p + token q/k/v projections (7 descs, 240 blocks) ----
    {
        GemmBatch ba; int base = 0, nd = 0;
        ba.d[nd++] = mkDesc(task_emb, DIM, task_proj_w, DIM, task_proj_b,
                            task_p, DIM, BATCH, DIM, DIM, base);
        base += blocksOf(BATCH, DIM);
        const float* tA[2] = { tokens_l1, tokens_l2 };
        int tT[2] = { 16, 64 };
        const float* tW[2][3] = { { wq1, wk1, wv1 }, { wq2, wk2, wv2 } };
        float* tC[2][3] = { { tq1, tk1, tv1 }, { tq2, tk2, tv2 } };
        for (int l = 0; l < 2; ++l)
            for (int w = 0; w < 3; ++w) {
                ba.d[nd++] = mkDesc(tA[l], DIM, tW[l][w], DIM, nullptr,
                                    tC[l][w], HDIM, tT[l], HDIM, DIM, base);
                base += blocksOf(tT[l], HDIM);
            }
        ba.nDesc = nd;
        gemm_bf16<<<dim3(base), dim3(256), 0, stream>>>(ba);
    }

    // ---- stage B: k_task/v_task + U_tok per head (12 descs, 456 blocks) ----
    {
        GemmBatch bb; int base = 0, nd = 0;
        const float* kw[2] = { wk1, wk2 };
        const float* vw[2] = { wv1, wv2 };
        float* kc[2] = { ktask1, ktask2 };
        float* vc[2] = { vtask1, vtask2 };
        for (int l = 0; l < 2; ++l) {
            bb.d[nd++] = mkDesc(task_p, DIM, kw[l], DIM, nullptr,
                                kc[l], HDIM, BATCH, HDIM, DIM, base);
            base += blocksOf(BATCH, HDIM);
            bb.d[nd++] = mkDesc(task_p, DIM, vw[l], DIM, nullptr,
                                vc[l], HDIM, BATCH, HDIM, DIM, base);
            base += blocksOf(BATCH, HDIM);
        }
        const float* fw[2] = { fcw1, fcw2 };
        float* tv[2] = { tv1, tv2 };
        float* ut[2] = { ut1, ut2 };
        int tT[2] = { 16, 64 };
        for (int l = 0; l < 2; ++l)
            for (int h = 0; h < HEADS; ++h) {
                bb.d[nd++] = mkDesc(tv[l] + h * DIM, HDIM, fw[l] + h * DIM, HDIM,
                                    nullptr, ut[l] + h * DIM, HDIM,
                                    tT[l], DIM, DIM, base);
                base += blocksOf(tT[l], DIM);
            }
        bb.nDesc = nd;
        gemm_bf16<<<dim3(base), dim3(256), 0, stream>>>(bb);
    }

    // ---- stage C: U_task per head per level (8 descs, 192 blocks) ----
    {
        GemmBatch bc; int base = 0, nd = 0;
        const float* fw[2] = { fcw1, fcw2 };
        float* vt[2] = { vtask1, vtask2 };
        float* utk[2] = { utask1, utask2 };
        for (int l = 0; l < 2; ++l)
            for (int h = 0; h < HEADS; ++h) {
                bc.d[nd++] = mkDesc(vt[l] + h * DIM, HDIM, fw[l] + h * DIM, HDIM,
                                    nullptr, utk[l] + h * DIM, HDIM,
                                    BATCH, DIM, DIM, base);
                base += blocksOf(BATCH, DIM);
            }
        bc.nDesc = nd;
        gemm_bf16<<<dim3(base), dim3(256), 0, stream>>>(bc);
    }

    // ---- stage D: both score levels, one dispatch ----
    {
        ScoreBatch sb;
        sb.d[0].tok_q = tq1; sb.d[0].tok_k = tk1; sb.d[0].k_task = ktask1;
        sb.d[0].U_tok = ut1; sb.d[0].U_task = utask1; sb.d[0].tokens = tokens_l1;
        sb.d[0].fcb = fcb1; sb.d[0].lng = lng1; sb.d[0].lnb = lnb1;
        sb.d[0].slng = slng1; sb.d[0].slnb = slnb1; sb.d[0].sw = sw1; sb.d[0].sbias = sb1;
        sb.d[0].T = 16; sb.d[0].outOff = 0; sb.d[0].blockBase = 0; sb.d[0].pad = 0;
        sb.d[1].tok_q = tq2; sb.d[1].tok_k = tk2; sb.d[1].k_task = ktask2;
        sb.d[1].U_tok = ut2; sb.d[1].U_task = utask2; sb.d[1].tokens = tokens_l2;
        sb.d[1].fcb = fcb2; sb.d[1].lng = lng2; sb.d[1].lnb = lnb2;
        sb.d[1].slng = slng2; sb.d[1].slnb = slnb2; sb.d[1].sw = sw2; sb.d[1].sbias = sb2;
        sb.d[1].T = 64; sb.d[1].outOff = 16; sb.d[1].blockBase = BATCH * 16; sb.d[1].pad = 0;
        score_kernel<<<dim3(BATCH * 16 + BATCH * 64), dim3(256), 0, stream>>>(sb, out);
    }
}